// Round 2
// baseline (290.754 us; speedup 1.0000x reference)
//
#include <hip/hip_runtime.h>

#define N_NODES 50000
#define N_EDGES 600000
#define N_PAD 50048        // N rounded up to 64 (mlp tiles)
#define IN_CH 64
#define HID 128
#define N_GRAPHS 64
#define CAP 64             // per-node edge-slot capacity (max degree ~28 for this input)
#define CAP_SHIFT 6

typedef __attribute__((ext_vector_type(8))) short bf16x8;
typedef __attribute__((ext_vector_type(4))) float f32x4;

// ---- bf16 helpers (manual, RNE) ----
__device__ __forceinline__ float bf2f(unsigned short u) {
    union { unsigned int i; float f; } v; v.i = ((unsigned int)u) << 16; return v.f;
}
__device__ __forceinline__ unsigned short f2bf(float f) {
    union { float f; unsigned int i; } v; v.f = f;
    unsigned int u = v.i;
    return (unsigned short)((u + 0x7FFFu + ((u >> 16) & 1u)) >> 16);
}

// 8B edge record: x = src(u16) | a0(bf16)<<16 ; y = a1(bf16) | a2(bf16)<<16

// ===========================================================================
// prep kernel (1 dispatch): zero deg+psum, 4 weight transposes, AND x->bf16.
// ===========================================================================
__global__ void prep_kernel(const float* __restrict__ x,
                            const float* __restrict__ w1a, const float* __restrict__ w1b,
                            const float* __restrict__ w2a, const float* __restrict__ w2b,
                            unsigned short* __restrict__ xbf,
                            unsigned short* __restrict__ waT1, unsigned short* __restrict__ wbT1,
                            unsigned short* __restrict__ waT2, unsigned short* __restrict__ wbT2,
                            int* __restrict__ deg, float* __restrict__ psum) {
    int i = blockIdx.x * blockDim.x + threadIdx.x;
    if (i < N_NODES * IN_CH) xbf[i] = f2bf(x[i]);
    if (i < N_NODES) deg[i] = 0;
    if (i < N_GRAPHS * HID) psum[i] = 0.f;
    if (i < IN_CH * HID) {               // w1a is [64,128]
        int k = i / HID, n = i % HID;
        waT1[n * IN_CH + k] = f2bf(w1a[i]);
    }
    if (i < HID * HID) {                 // the three [128,128] weights
        int k = i / HID, n = i % HID;
        wbT1[n * HID + k] = f2bf(w1b[i]);
        waT2[n * HID + k] = f2bf(w2a[i]);
        wbT2[n * HID + k] = f2bf(w2b[i]);
    }
}

// ===========================================================================
// Single-pass edge build. R2: 1 edge/thread (was 4) — grid 587->2344 blocks,
// ~9 -> 32 waves/CU resident; each thread owns ONE atomic->store chain so
// occupancy, not chain latency, sets the rate.
// ===========================================================================
__global__ void build_kernel(const int* __restrict__ ei,
                             const float* __restrict__ ea,
                             int* __restrict__ deg,
                             uint2* __restrict__ edata) {
    int i = blockIdx.x * blockDim.x + threadIdx.x;
    if (i >= N_EDGES) return;
    int s = ei[i];
    int d = ei[N_EDGES + i];
    float a0 = ea[3 * (size_t)i], a1 = ea[3 * (size_t)i + 1], a2 = ea[3 * (size_t)i + 2];
    int p = atomicAdd(&deg[d], 1);
    if (p < CAP)
        edata[((size_t)d << CAP_SHIFT) + p] =
            make_uint2((unsigned)s | ((unsigned)f2bf(a0) << 16),
                       (unsigned)f2bf(a1) | ((unsigned)f2bf(a2) << 16));
}

// ===========================================================================
// Layer-1 gather (K=64). R2: explicit 2-stage software pipeline over 4-edge
// batches — next batch's edata load + row gathers issue before current
// batch's compute, breaking the edata->gather->compute serial chain.
// ===========================================================================
__global__ void gather64_kernel(const unsigned short* __restrict__ xin,  // bf16 [N,64]
                                const uint2* __restrict__ edata,
                                const int* __restrict__ deg,
                                const float* __restrict__ elw,  // [3, 64]
                                const float* __restrict__ elb,  // [64]
                                unsigned short* __restrict__ sg) {  // bf16 [N, 64]
    constexpr int K = IN_CH;
    constexpr int NPB = 8;
    const int node0 = blockIdx.x * NPB;
    const int t = threadIdx.x;  // 0..127
    const int c = t & 63, half = t >> 6;
    const float w0 = elw[c], w1 = elw[K + c], w2 = elw[2 * K + c], eb = elb[c];

    auto term = [&](uint2 e, unsigned short row) -> float {
        float ev = bf2f((unsigned short)(e.x >> 16)) * w0 +
                   bf2f((unsigned short)(e.y & 0xFFFF)) * w1 +
                   bf2f((unsigned short)(e.y >> 16)) * w2 + eb;
        float m = bf2f(row) + ev;
        return m > 0.f ? m : 0.f;
    };

#define G64_LI(e_, r_) do {                                        \
        e_[0] = edata[j]; e_[1] = edata[j + 1];                    \
        e_[2] = edata[j + 2]; e_[3] = edata[j + 3];                \
        r_[0] = xin[(size_t)(e_[0].x & 0xFFFF) * K + c];           \
        r_[1] = xin[(size_t)(e_[1].x & 0xFFFF) * K + c];           \
        r_[2] = xin[(size_t)(e_[2].x & 0xFFFF) * K + c];           \
        r_[3] = xin[(size_t)(e_[3].x & 0xFFFF) * K + c];           \
        j += 4;                                                    \
    } while (0)
#define G64_C(e_, r_) do {                                         \
        acc += term(e_[0], r_[0]) + term(e_[1], r_[1])             \
             + term(e_[2], r_[2]) + term(e_[3], r_[3]);            \
    } while (0)

    for (int i = 0; i < NPB; i += 2) {
        int node = node0 + i + half;
        float acc = bf2f(xin[(size_t)node * K + c]);
        int dn = deg[node]; if (dn > CAP) dn = CAP;
        int j = node << CAP_SHIFT;
        const int je = j + dn;
        int m = dn >> 2;

        uint2 e0_[4], e1_[4];
        unsigned short r0_[4], r1_[4];
        if (m > 0) {
            G64_LI(e0_, r0_);
            int k = m - 1;
            while (k >= 2) {
                G64_LI(e1_, r1_);
                G64_C(e0_, r0_);
                G64_LI(e0_, r0_);
                G64_C(e1_, r1_);
                k -= 2;
            }
            if (k == 1) {
                G64_LI(e1_, r1_);
                G64_C(e0_, r0_);
                G64_C(e1_, r1_);
            } else {
                G64_C(e0_, r0_);
            }
        }
        for (; j < je; j++) {
            uint2 e0 = edata[j];
            acc += term(e0, xin[(size_t)(e0.x & 0xFFFF) * K + c]);
        }
        sg[(size_t)node * K + c] = f2bf(acc);
    }
#undef G64_LI
#undef G64_C
}

// ===========================================================================
// Layer-2 gather (K=128, bf16), packed u32 lanes, paired-lockstep.
// R2: 2-stage software pipeline over 4-edge pair-batches (8 gathers/stage).
// ===========================================================================
__global__ void gather128_kernel(const unsigned short* __restrict__ xin,  // bf16 [N,128]
                                 const uint2* __restrict__ edata,
                                 const int* __restrict__ deg,
                                 const float* __restrict__ elw,  // [3, 128]
                                 const float* __restrict__ elb,  // [128]
                                 unsigned short* __restrict__ sg) {  // bf16 [N, 128]
    const int t = threadIdx.x;
    const int w = t >> 6, l = t & 63;
    const unsigned* x32 = (const unsigned*)xin;       // row = 64 uints
    unsigned* sg32 = (unsigned*)sg;
    const int c0 = 2 * l;
    const float w00 = elw[c0],           w01 = elw[c0 + 1];
    const float w10 = elw[HID + c0],     w11 = elw[HID + c0 + 1];
    const float w20 = elw[2 * HID + c0], w21 = elw[2 * HID + c0 + 1];
    const float eb0 = elb[c0],           eb1 = elb[c0 + 1];
    const int node0 = (blockIdx.x * 4 + w) * 4;

    auto term2 = [&](uint2 e, unsigned r, float& p0, float& p1) {
        float A0 = bf2f((unsigned short)(e.x >> 16));
        float A1 = bf2f((unsigned short)(e.y & 0xFFFF));
        float A2 = bf2f((unsigned short)(e.y >> 16));
        float ev0 = A0 * w00 + A1 * w10 + A2 * w20 + eb0;
        float ev1 = A0 * w01 + A1 * w11 + A2 * w21 + eb1;
        float m0 = bf2f((unsigned short)(r & 0xFFFF)) + ev0;
        float m1 = bf2f((unsigned short)(r >> 16)) + ev1;
        p0 += m0 > 0.f ? m0 : 0.f;
        p1 += m1 > 0.f ? m1 : 0.f;
    };

#define G128_LI(eA_, eB_, rA_, rB_) do {                             \
        eA_[0] = edata[ja]; eA_[1] = edata[ja + 1];                  \
        eA_[2] = edata[ja + 2]; eA_[3] = edata[ja + 3];              \
        eB_[0] = edata[jb]; eB_[1] = edata[jb + 1];                  \
        eB_[2] = edata[jb + 2]; eB_[3] = edata[jb + 3];              \
        rA_[0] = x32[(size_t)(eA_[0].x & 0xFFFF) * 64 + l];          \
        rA_[1] = x32[(size_t)(eA_[1].x & 0xFFFF) * 64 + l];          \
        rA_[2] = x32[(size_t)(eA_[2].x & 0xFFFF) * 64 + l];          \
        rA_[3] = x32[(size_t)(eA_[3].x & 0xFFFF) * 64 + l];          \
        rB_[0] = x32[(size_t)(eB_[0].x & 0xFFFF) * 64 + l];          \
        rB_[1] = x32[(size_t)(eB_[1].x & 0xFFFF) * 64 + l];          \
        rB_[2] = x32[(size_t)(eB_[2].x & 0xFFFF) * 64 + l];          \
        rB_[3] = x32[(size_t)(eB_[3].x & 0xFFFF) * 64 + l];          \
        ja += 4; jb += 4;                                            \
    } while (0)
#define G128_C(eA_, eB_, rA_, rB_) do {                              \
        term2(eA_[0], rA_[0], a0, a1); term2(eA_[1], rA_[1], a0, a1); \
        term2(eA_[2], rA_[2], a0, a1); term2(eA_[3], rA_[3], a0, a1); \
        term2(eB_[0], rB_[0], b0, b1); term2(eB_[1], rB_[1], b0, b1); \
        term2(eB_[2], rB_[2], b0, b1); term2(eB_[3], rB_[3], b0, b1); \
    } while (0)

    for (int ni = 0; ni < 4; ni += 2) {
        int nA = node0 + ni, nB = node0 + ni + 1;
        unsigned svA = x32[(size_t)nA * 64 + l];
        unsigned svB = x32[(size_t)nB * 64 + l];
        float a0 = bf2f((unsigned short)(svA & 0xFFFF));
        float a1 = bf2f((unsigned short)(svA >> 16));
        float b0 = bf2f((unsigned short)(svB & 0xFFFF));
        float b1 = bf2f((unsigned short)(svB >> 16));

        int dA = deg[nA]; if (dA > CAP) dA = CAP;
        int dB = deg[nB]; if (dB > CAP) dB = CAP;
        int ja = nA << CAP_SHIFT; const int jaE = ja + dA;
        int jb = nB << CAP_SHIFT; const int jbE = jb + dB;

        int m = ((dA < dB) ? dA : dB) >> 2;   // lockstep pair-batches
        uint2 eA0_[4], eB0_[4], eA1_[4], eB1_[4];
        unsigned rA0_[4], rB0_[4], rA1_[4], rB1_[4];
        if (m > 0) {
            G128_LI(eA0_, eB0_, rA0_, rB0_);
            int k = m - 1;
            while (k >= 2) {
                G128_LI(eA1_, eB1_, rA1_, rB1_);
                G128_C(eA0_, eB0_, rA0_, rB0_);
                G128_LI(eA0_, eB0_, rA0_, rB0_);
                G128_C(eA1_, eB1_, rA1_, rB1_);
                k -= 2;
            }
            if (k == 1) {
                G128_LI(eA1_, eB1_, rA1_, rB1_);
                G128_C(eA0_, eB0_, rA0_, rB0_);
                G128_C(eA1_, eB1_, rA1_, rB1_);
            } else {
                G128_C(eA0_, eB0_, rA0_, rB0_);
            }
        }
        // remainders (imbalanced tails): 4-wide then singles
        for (; ja + 4 <= jaE; ja += 4) {
            uint2 e0 = edata[ja], e1 = edata[ja + 1], e2 = edata[ja + 2], e3 = edata[ja + 3];
            unsigned r0 = x32[(size_t)(e0.x & 0xFFFF) * 64 + l];
            unsigned r1 = x32[(size_t)(e1.x & 0xFFFF) * 64 + l];
            unsigned r2 = x32[(size_t)(e2.x & 0xFFFF) * 64 + l];
            unsigned r3 = x32[(size_t)(e3.x & 0xFFFF) * 64 + l];
            term2(e0, r0, a0, a1); term2(e1, r1, a0, a1);
            term2(e2, r2, a0, a1); term2(e3, r3, a0, a1);
        }
        for (; ja < jaE; ja++) {
            uint2 e0 = edata[ja];
            term2(e0, x32[(size_t)(e0.x & 0xFFFF) * 64 + l], a0, a1);
        }
        for (; jb + 4 <= jbE; jb += 4) {
            uint2 e0 = edata[jb], e1 = edata[jb + 1], e2 = edata[jb + 2], e3 = edata[jb + 3];
            unsigned r0 = x32[(size_t)(e0.x & 0xFFFF) * 64 + l];
            unsigned r1 = x32[(size_t)(e1.x & 0xFFFF) * 64 + l];
            unsigned r2 = x32[(size_t)(e2.x & 0xFFFF) * 64 + l];
            unsigned r3 = x32[(size_t)(e3.x & 0xFFFF) * 64 + l];
            term2(e0, r0, b0, b1); term2(e1, r1, b0, b1);
            term2(e2, r2, b0, b1); term2(e3, r3, b0, b1);
        }
        for (; jb < jbE; jb++) {
            uint2 e0 = edata[jb];
            term2(e0, x32[(size_t)(e0.x & 0xFFFF) * 64 + l], b0, b1);
        }
        sg32[(size_t)nA * 64 + l] = (unsigned)f2bf(a0) | ((unsigned)f2bf(a1) << 16);
        sg32[(size_t)nB * 64 + l] = (unsigned)f2bf(b0) | ((unsigned)f2bf(b1) << 16);
    }
#undef G128_LI
#undef G128_C
}

// ===========================================================================
// Standalone MFMA MLP — R12-proven (MFMA body + LDS-staged epilogue).
// ===========================================================================
template <int K, bool POOL>
__global__ __launch_bounds__(256)
void mlp_mfma_kernel(const unsigned short* __restrict__ sg,   // bf16 [N_PAD, K]
                     const unsigned short* __restrict__ waT,  // bf16 [HID, K]
                     const float* __restrict__ ba,
                     const unsigned short* __restrict__ wbT,  // bf16 [HID, HID]
                     const float* __restrict__ bb,
                     void* __restrict__ outv,                 // bf16 h or f32 psum
                     const int* __restrict__ batch) {
    constexpr int HSTR = 136;      // shorts
    constexpr int OSTR = HID + 4;  // f32
    __shared__ __align__(16) unsigned short sHid[4][16 * HSTR];  // 17.4 KB
    __shared__ __align__(16) float sOut[64 * OSTR];              // 33.8 KB
    const int t = threadIdx.x;
    const int w = t >> 6, l = t & 63;
    const int i16 = l & 15, q = l >> 4;
    const int blk0 = blockIdx.x * 64;
    const int row0 = blk0 + w * 16;   // this wave's 16 rows

    // ---- layer A: [16 x K] @ waT -> relu -> own LDS buffer ----
    bf16x8 aA[K / 32];
    #pragma unroll
    for (int s = 0; s < K / 32; s++)
        aA[s] = *(const bf16x8*)&sg[(size_t)(row0 + i16) * K + s * 32 + q * 8];
    unsigned short* myHid = sHid[w];
    #pragma unroll
    for (int ct = 0; ct < 8; ct++) {
        int col = ct * 16 + i16;
        float bv = ba[col];
        f32x4 acc = (f32x4){bv, bv, bv, bv};
        #pragma unroll
        for (int s = 0; s < K / 32; s++) {
            bf16x8 b = *(const bf16x8*)&waT[(size_t)col * K + s * 32 + q * 8];
            acc = __builtin_amdgcn_mfma_f32_16x16x32_bf16(aA[s], b, acc, 0, 0, 0);
        }
        #pragma unroll
        for (int r = 0; r < 4; r++) {
            float v = acc[r] > 0.f ? acc[r] : 0.f;
            myHid[(q * 4 + r) * HSTR + col] = f2bf(v);
        }
    }
    __syncthreads();

    // ---- layer B: [16 x 128] @ wbT -> relu -> sOut (f32 LDS) ----
    bf16x8 aB[4];
    #pragma unroll
    for (int s = 0; s < 4; s++)
        aB[s] = *(const bf16x8*)&myHid[i16 * HSTR + s * 32 + q * 8];
    #pragma unroll
    for (int ct = 0; ct < 8; ct++) {
        int col = ct * 16 + i16;
        float bv = bb[col];
        f32x4 acc = (f32x4){bv, bv, bv, bv};
        #pragma unroll
        for (int s = 0; s < 4; s++) {
            bf16x8 b = *(const bf16x8*)&wbT[(size_t)col * HID + s * 32 + q * 8];
            acc = __builtin_amdgcn_mfma_f32_16x16x32_bf16(aB[s], b, acc, 0, 0, 0);
        }
        #pragma unroll
        for (int r = 0; r < 4; r++) {
            float v = acc[r] > 0.f ? acc[r] : 0.f;
            sOut[(w * 16 + q * 4 + r) * OSTR + col] = v;
        }
    }
    __syncthreads();

    // ---- epilogue (R12-proven) ----
    if (POOL) {
        if (t < HID) {
            float* psum = (float*)outv;
            float acc = 0.f;
            int curg = batch[blk0];
            for (int row = 0; row < 64; row++) {
                int node = blk0 + row;
                if (node >= N_NODES) break;
                int g = batch[node];
                if (g != curg) {
                    atomicAdd(&psum[curg * HID + t], acc);
                    acc = 0.f; curg = g;
                }
                acc += sOut[row * OSTR + t];
            }
            atomicAdd(&psum[curg * HID + t], acc);
        }
    } else {
        unsigned short* hout = (unsigned short*)outv;
        for (int idx = t; idx < 64 * 16; idx += 256) {
            int row = idx >> 4, ch = idx & 15;   // ch = 16B chunk (8 bf16)
            int node = blk0 + row;
            if (node < N_NODES) {
                float4 f0 = *(const float4*)&sOut[row * OSTR + ch * 8];
                float4 f1 = *(const float4*)&sOut[row * OSTR + ch * 8 + 4];
                uint4 u;
                u.x = (unsigned)f2bf(f0.x) | ((unsigned)f2bf(f0.y) << 16);
                u.y = (unsigned)f2bf(f0.z) | ((unsigned)f2bf(f0.w) << 16);
                u.z = (unsigned)f2bf(f1.x) | ((unsigned)f2bf(f1.y) << 16);
                u.w = (unsigned)f2bf(f1.z) | ((unsigned)f2bf(f1.w) << 16);
                *(uint4*)&hout[(size_t)node * HID + ch * 8] = u;
            }
        }
    }
}

// ---------------------------------------------------------------------------
// Pool mean: batch is SORTED -> count[g] by binary search (wave-uniform).
// ---------------------------------------------------------------------------
__global__ void pool_div_kernel(const float* __restrict__ sums,
                                const int* __restrict__ batch,
                                float* __restrict__ out) {
    int i = blockIdx.x * blockDim.x + threadIdx.x;
    if (i >= N_GRAPHS * HID) return;
    int g = i / HID;
    int lo = 0, hi = N_NODES;
    while (lo < hi) { int mid = (lo + hi) >> 1; if (batch[mid] < g) lo = mid + 1; else hi = mid; }
    int start = lo;
    lo = 0; hi = N_NODES;
    while (lo < hi) { int mid = (lo + hi) >> 1; if (batch[mid] <= g) lo = mid + 1; else hi = mid; }
    float c = (float)(lo - start);
    out[i] = sums[i] / (c > 1.0f ? c : 1.0f);
}

extern "C" void kernel_launch(void* const* d_in, const int* in_sizes, int n_in,
                              void* d_out, int out_size, void* d_ws, size_t ws_size,
                              hipStream_t stream) {
    const float* x    = (const float*)d_in[0];
    const int*   ei   = (const int*)d_in[1];
    const float* ea   = (const float*)d_in[2];
    const int*   batch= (const int*)d_in[3];
    const float* el1w = (const float*)d_in[4];
    const float* el1b = (const float*)d_in[5];
    const float* w1a  = (const float*)d_in[6];
    const float* b1a  = (const float*)d_in[7];
    const float* w1b  = (const float*)d_in[8];
    const float* b1b  = (const float*)d_in[9];
    const float* el2w = (const float*)d_in[10];
    const float* el2b = (const float*)d_in[11];
    const float* w2a  = (const float*)d_in[12];
    const float* b2a  = (const float*)d_in[13];
    const float* w2b  = (const float*)d_in[14];
    const float* b2b  = (const float*)d_in[15];
    float* out = (float*)d_out;

    // workspace layout (16B-aligned sections)
    uint2* edata    = (uint2*)d_ws;                        // [N*CAP] 8B records  25.6 MB
    float* psum     = (float*)(edata + (size_t)N_NODES * CAP);  // [G*HID] 8192 f32
    int*   deg      = (int*)(psum + N_GRAPHS * HID);       // [N]
    // ints after edata: 8192 + 50000 = 58192 (16B multiple)
    unsigned short* hbf  = (unsigned short*)((char*)psum + (size_t)58192 * 4);  // bf16 [N,HID]
    unsigned short* sgbuf= hbf + (size_t)N_NODES * HID;  // bf16 [N_PAD, 128] (layer1 uses stride 64)
    unsigned short* waT1 = sgbuf + (size_t)N_PAD * HID;  // bf16 [128, 64]
    unsigned short* wbT1 = waT1 + HID * IN_CH;           // bf16 [128, 128]
    unsigned short* waT2 = wbT1 + HID * HID;             // bf16 [128, 128]
    unsigned short* wbT2 = waT2 + HID * HID;             // bf16 [128, 128]
    unsigned short* xbf  = wbT2 + HID * HID;             // bf16 [N, 64]

    // ---- prep (1 dispatch): zero deg+psum, transpose weights, x->bf16 ----
    prep_kernel<<<(N_NODES * IN_CH) / 256, 256, 0, stream>>>(
        x, w1a, w1b, w2a, w2b, xbf, waT1, wbT1, waT2, wbT2, deg, psum);
    // ---- edge build: one dispatch, 1 edge/thread, fixed-capacity buckets ----
    build_kernel<<<(N_EDGES + 255) / 256, 256, 0, stream>>>(ei, ea, deg, edata);

    // ---- layer 1: bf16 gather -> sg ; MFMA MLP -> hbf (bf16) ----
    gather64_kernel<<<N_NODES / 8, 128, 0, stream>>>(
        xbf, edata, deg, el1w, el1b, sgbuf);
    mlp_mfma_kernel<IN_CH, false><<<N_PAD / 64, 256, 0, stream>>>(
        sgbuf, waT1, b1a, wbT1, b1b, hbf, nullptr);

    // ---- layer 2: paired-lockstep bf16 gather ; MFMA MLP + LDS pool ----
    gather128_kernel<<<N_NODES / 16, 256, 0, stream>>>(
        hbf, edata, deg, el2w, el2b, sgbuf);
    mlp_mfma_kernel<HID, true><<<N_PAD / 64, 256, 0, stream>>>(
        sgbuf, waT2, b2a, wbT2, b2b, psum, batch);

    // ---- mean (count via binary search on sorted batch) ----
    pool_div_kernel<<<(N_GRAPHS * HID + 255) / 256, 256, 0, stream>>>(psum, batch, out);
}

// Round 3
// 268.684 us; speedup vs baseline: 1.0821x; 1.0821x over previous
//
#include <hip/hip_runtime.h>

#define N_NODES 50000
#define N_EDGES 600000
#define N_PAD 50048        // N rounded up to 64 (mlp tiles)
#define IN_CH 64
#define HID 128
#define N_GRAPHS 64
#define CAP 64             // per-node edge-slot capacity (max degree ~28 for this input)
#define CAP_SHIFT 6

typedef __attribute__((ext_vector_type(8))) short bf16x8;
typedef __attribute__((ext_vector_type(4))) float f32x4;

// ---- bf16 helpers (manual, RNE) ----
__device__ __forceinline__ float bf2f(unsigned short u) {
    union { unsigned int i; float f; } v; v.i = ((unsigned int)u) << 16; return v.f;
}
__device__ __forceinline__ unsigned short f2bf(float f) {
    union { float f; unsigned int i; } v; v.f = f;
    unsigned int u = v.i;
    return (unsigned short)((u + 0x7FFFu + ((u >> 16) & 1u)) >> 16);
}

// 8B edge record: x = src(u16) | a0(bf16)<<16 ; y = a1(bf16) | a2(bf16)<<16

// ===========================================================================
// prep kernel (1 dispatch): zero deg+psum, 4 weight transposes, AND x->bf16.
// ===========================================================================
__global__ void prep_kernel(const float* __restrict__ x,
                            const float* __restrict__ w1a, const float* __restrict__ w1b,
                            const float* __restrict__ w2a, const float* __restrict__ w2b,
                            unsigned short* __restrict__ xbf,
                            unsigned short* __restrict__ waT1, unsigned short* __restrict__ wbT1,
                            unsigned short* __restrict__ waT2, unsigned short* __restrict__ wbT2,
                            int* __restrict__ deg, float* __restrict__ psum) {
    int i = blockIdx.x * blockDim.x + threadIdx.x;
    if (i < N_NODES * IN_CH) xbf[i] = f2bf(x[i]);
    if (i < N_NODES) deg[i] = 0;
    if (i < N_GRAPHS * HID) psum[i] = 0.f;
    if (i < IN_CH * HID) {               // w1a is [64,128]
        int k = i / HID, n = i % HID;
        waT1[n * IN_CH + k] = f2bf(w1a[i]);
    }
    if (i < HID * HID) {                 // the three [128,128] weights
        int k = i / HID, n = i % HID;
        wbT1[n * HID + k] = f2bf(w1b[i]);
        waT2[n * HID + k] = f2bf(w2a[i]);
        wbT2[n * HID + k] = f2bf(w2b[i]);
    }
}

// ===========================================================================
// Single-pass edge build: 1 edge/thread (R2 change, kept — grid 2344 blocks,
// each thread owns ONE atomic->store chain; occupancy hides the latency).
// ===========================================================================
__global__ void build_kernel(const int* __restrict__ ei,
                             const float* __restrict__ ea,
                             int* __restrict__ deg,
                             uint2* __restrict__ edata) {
    int i = blockIdx.x * blockDim.x + threadIdx.x;
    if (i >= N_EDGES) return;
    int s = ei[i];
    int d = ei[N_EDGES + i];
    float a0 = ea[3 * (size_t)i], a1 = ea[3 * (size_t)i + 1], a2 = ea[3 * (size_t)i + 2];
    int p = atomicAdd(&deg[d], 1);
    if (p < CAP)
        edata[((size_t)d << CAP_SHIFT) + p] =
            make_uint2((unsigned)s | ((unsigned)f2bf(a0) << 16),
                       (unsigned)f2bf(a1) | ((unsigned)f2bf(a2) << 16));
}

// ===========================================================================
// Layer-1 gather (K=64) — R1-proven body (VGPR 40 class; the R2 explicit
// pipeline pushed VGPR to 64 = occupancy cliff, reverted). R3: NPB 8->4,
// grid 2x, halving per-thread serial node count for finer load balance.
// ===========================================================================
__global__ void gather64_kernel(const unsigned short* __restrict__ xin,  // bf16 [N,64]
                                const uint2* __restrict__ edata,
                                const int* __restrict__ deg,
                                const float* __restrict__ elw,  // [3, 64]
                                const float* __restrict__ elb,  // [64]
                                unsigned short* __restrict__ sg) {  // bf16 [N, 64]
    constexpr int K = IN_CH;
    constexpr int NPB = 4;
    const int node0 = blockIdx.x * NPB;
    const int t = threadIdx.x;  // 0..127
    const int c = t & 63, half = t >> 6;
    const float w0 = elw[c], w1 = elw[K + c], w2 = elw[2 * K + c], eb = elb[c];

    auto term = [&](uint2 e, unsigned short row) -> float {
        float ev = bf2f((unsigned short)(e.x >> 16)) * w0 +
                   bf2f((unsigned short)(e.y & 0xFFFF)) * w1 +
                   bf2f((unsigned short)(e.y >> 16)) * w2 + eb;
        float m = bf2f(row) + ev;
        return m > 0.f ? m : 0.f;
    };

    for (int i = 0; i < NPB; i += 2) {
        int node = node0 + i + half;
        float acc = bf2f(xin[(size_t)node * K + c]);
        int dn = deg[node]; if (dn > CAP) dn = CAP;
        int jb = node << CAP_SHIFT, je = jb + dn;
        int j = jb;
        for (; j + 8 <= je; j += 8) {
            uint2 e0 = edata[j],     e1 = edata[j + 1], e2 = edata[j + 2], e3 = edata[j + 3];
            uint2 e4 = edata[j + 4], e5 = edata[j + 5], e6 = edata[j + 6], e7 = edata[j + 7];
            unsigned short r0 = xin[(size_t)(e0.x & 0xFFFF) * K + c];
            unsigned short r1 = xin[(size_t)(e1.x & 0xFFFF) * K + c];
            unsigned short r2 = xin[(size_t)(e2.x & 0xFFFF) * K + c];
            unsigned short r3 = xin[(size_t)(e3.x & 0xFFFF) * K + c];
            unsigned short r4 = xin[(size_t)(e4.x & 0xFFFF) * K + c];
            unsigned short r5 = xin[(size_t)(e5.x & 0xFFFF) * K + c];
            unsigned short r6 = xin[(size_t)(e6.x & 0xFFFF) * K + c];
            unsigned short r7 = xin[(size_t)(e7.x & 0xFFFF) * K + c];
            acc += term(e0, r0) + term(e1, r1) + term(e2, r2) + term(e3, r3)
                 + term(e4, r4) + term(e5, r5) + term(e6, r6) + term(e7, r7);
        }
        for (; j + 4 <= je; j += 4) {
            uint2 e0 = edata[j], e1 = edata[j + 1], e2 = edata[j + 2], e3 = edata[j + 3];
            unsigned short r0 = xin[(size_t)(e0.x & 0xFFFF) * K + c];
            unsigned short r1 = xin[(size_t)(e1.x & 0xFFFF) * K + c];
            unsigned short r2 = xin[(size_t)(e2.x & 0xFFFF) * K + c];
            unsigned short r3 = xin[(size_t)(e3.x & 0xFFFF) * K + c];
            acc += term(e0, r0) + term(e1, r1) + term(e2, r2) + term(e3, r3);
        }
        for (; j < je; j++) {
            uint2 e0 = edata[j];
            acc += term(e0, xin[(size_t)(e0.x & 0xFFFF) * K + c]);
        }
        sg[(size_t)node * K + c] = f2bf(acc);
    }
}

// ===========================================================================
// Layer-2 gather (K=128, bf16), packed u32 lanes, paired-lockstep — R1-proven
// body. R3: ONE pair per wave (was two sequential pairs), grid 2x.
// ===========================================================================
__global__ void gather128_kernel(const unsigned short* __restrict__ xin,  // bf16 [N,128]
                                 const uint2* __restrict__ edata,
                                 const int* __restrict__ deg,
                                 const float* __restrict__ elw,  // [3, 128]
                                 const float* __restrict__ elb,  // [128]
                                 unsigned short* __restrict__ sg) {  // bf16 [N, 128]
    const int t = threadIdx.x;
    const int w = t >> 6, l = t & 63;
    const unsigned* x32 = (const unsigned*)xin;       // row = 64 uints
    unsigned* sg32 = (unsigned*)sg;
    const int c0 = 2 * l;
    const float w00 = elw[c0],           w01 = elw[c0 + 1];
    const float w10 = elw[HID + c0],     w11 = elw[HID + c0 + 1];
    const float w20 = elw[2 * HID + c0], w21 = elw[2 * HID + c0 + 1];
    const float eb0 = elb[c0],           eb1 = elb[c0 + 1];
    const int nA = (blockIdx.x * 4 + w) * 2;
    const int nB = nA + 1;

    unsigned svA = x32[(size_t)nA * 64 + l];
    unsigned svB = x32[(size_t)nB * 64 + l];
    float a0 = bf2f((unsigned short)(svA & 0xFFFF));
    float a1 = bf2f((unsigned short)(svA >> 16));
    float b0 = bf2f((unsigned short)(svB & 0xFFFF));
    float b1 = bf2f((unsigned short)(svB >> 16));

    auto term2 = [&](uint2 e, unsigned r, float& p0, float& p1) {
        float A0 = bf2f((unsigned short)(e.x >> 16));
        float A1 = bf2f((unsigned short)(e.y & 0xFFFF));
        float A2 = bf2f((unsigned short)(e.y >> 16));
        float ev0 = A0 * w00 + A1 * w10 + A2 * w20 + eb0;
        float ev1 = A0 * w01 + A1 * w11 + A2 * w21 + eb1;
        float m0 = bf2f((unsigned short)(r & 0xFFFF)) + ev0;
        float m1 = bf2f((unsigned short)(r >> 16)) + ev1;
        p0 += m0 > 0.f ? m0 : 0.f;
        p1 += m1 > 0.f ? m1 : 0.f;
    };

    int dA = deg[nA]; if (dA > CAP) dA = CAP;
    int dB = deg[nB]; if (dB > CAP) dB = CAP;
    int ja = nA << CAP_SHIFT; const int jaE = ja + dA;
    int jb = nB << CAP_SHIFT; const int jbE = jb + dB;
    while (ja + 4 <= jaE && jb + 4 <= jbE) {
        uint2 eA0 = edata[ja],     eA1 = edata[ja + 1], eA2 = edata[ja + 2], eA3 = edata[ja + 3];
        uint2 eB0 = edata[jb],     eB1 = edata[jb + 1], eB2 = edata[jb + 2], eB3 = edata[jb + 3];
        unsigned rA0 = x32[(size_t)(eA0.x & 0xFFFF) * 64 + l];
        unsigned rA1 = x32[(size_t)(eA1.x & 0xFFFF) * 64 + l];
        unsigned rA2 = x32[(size_t)(eA2.x & 0xFFFF) * 64 + l];
        unsigned rA3 = x32[(size_t)(eA3.x & 0xFFFF) * 64 + l];
        unsigned rB0 = x32[(size_t)(eB0.x & 0xFFFF) * 64 + l];
        unsigned rB1 = x32[(size_t)(eB1.x & 0xFFFF) * 64 + l];
        unsigned rB2 = x32[(size_t)(eB2.x & 0xFFFF) * 64 + l];
        unsigned rB3 = x32[(size_t)(eB3.x & 0xFFFF) * 64 + l];
        term2(eA0, rA0, a0, a1); term2(eA1, rA1, a0, a1);
        term2(eA2, rA2, a0, a1); term2(eA3, rA3, a0, a1);
        term2(eB0, rB0, b0, b1); term2(eB1, rB1, b0, b1);
        term2(eB2, rB2, b0, b1); term2(eB3, rB3, b0, b1);
        ja += 4; jb += 4;
    }
    for (; ja + 4 <= jaE; ja += 4) {
        uint2 e0 = edata[ja], e1 = edata[ja + 1], e2 = edata[ja + 2], e3 = edata[ja + 3];
        unsigned r0 = x32[(size_t)(e0.x & 0xFFFF) * 64 + l];
        unsigned r1 = x32[(size_t)(e1.x & 0xFFFF) * 64 + l];
        unsigned r2 = x32[(size_t)(e2.x & 0xFFFF) * 64 + l];
        unsigned r3 = x32[(size_t)(e3.x & 0xFFFF) * 64 + l];
        term2(e0, r0, a0, a1); term2(e1, r1, a0, a1);
        term2(e2, r2, a0, a1); term2(e3, r3, a0, a1);
    }
    for (; ja < jaE; ja++) {
        uint2 e0 = edata[ja];
        term2(e0, x32[(size_t)(e0.x & 0xFFFF) * 64 + l], a0, a1);
    }
    for (; jb + 4 <= jbE; jb += 4) {
        uint2 e0 = edata[jb], e1 = edata[jb + 1], e2 = edata[jb + 2], e3 = edata[jb + 3];
        unsigned r0 = x32[(size_t)(e0.x & 0xFFFF) * 64 + l];
        unsigned r1 = x32[(size_t)(e1.x & 0xFFFF) * 64 + l];
        unsigned r2 = x32[(size_t)(e2.x & 0xFFFF) * 64 + l];
        unsigned r3 = x32[(size_t)(e3.x & 0xFFFF) * 64 + l];
        term2(e0, r0, b0, b1); term2(e1, r1, b0, b1);
        term2(e2, r2, b0, b1); term2(e3, r3, b0, b1);
    }
    for (; jb < jbE; jb++) {
        uint2 e0 = edata[jb];
        term2(e0, x32[(size_t)(e0.x & 0xFFFF) * 64 + l], b0, b1);
    }
    sg32[(size_t)nA * 64 + l] = (unsigned)f2bf(a0) | ((unsigned)f2bf(a1) << 16);
    sg32[(size_t)nB * 64 + l] = (unsigned)f2bf(b0) | ((unsigned)f2bf(b1) << 16);
}

// ===========================================================================
// Standalone MFMA MLP — R12-proven (MFMA body + LDS-staged epilogue).
// ===========================================================================
template <int K, bool POOL>
__global__ __launch_bounds__(256)
void mlp_mfma_kernel(const unsigned short* __restrict__ sg,   // bf16 [N_PAD, K]
                     const unsigned short* __restrict__ waT,  // bf16 [HID, K]
                     const float* __restrict__ ba,
                     const unsigned short* __restrict__ wbT,  // bf16 [HID, HID]
                     const float* __restrict__ bb,
                     void* __restrict__ outv,                 // bf16 h or f32 psum
                     const int* __restrict__ batch) {
    constexpr int HSTR = 136;      // shorts
    constexpr int OSTR = HID + 4;  // f32
    __shared__ __align__(16) unsigned short sHid[4][16 * HSTR];  // 17.4 KB
    __shared__ __align__(16) float sOut[64 * OSTR];              // 33.8 KB
    const int t = threadIdx.x;
    const int w = t >> 6, l = t & 63;
    const int i16 = l & 15, q = l >> 4;
    const int blk0 = blockIdx.x * 64;
    const int row0 = blk0 + w * 16;   // this wave's 16 rows

    // ---- layer A: [16 x K] @ waT -> relu -> own LDS buffer ----
    bf16x8 aA[K / 32];
    #pragma unroll
    for (int s = 0; s < K / 32; s++)
        aA[s] = *(const bf16x8*)&sg[(size_t)(row0 + i16) * K + s * 32 + q * 8];
    unsigned short* myHid = sHid[w];
    #pragma unroll
    for (int ct = 0; ct < 8; ct++) {
        int col = ct * 16 + i16;
        float bv = ba[col];
        f32x4 acc = (f32x4){bv, bv, bv, bv};
        #pragma unroll
        for (int s = 0; s < K / 32; s++) {
            bf16x8 b = *(const bf16x8*)&waT[(size_t)col * K + s * 32 + q * 8];
            acc = __builtin_amdgcn_mfma_f32_16x16x32_bf16(aA[s], b, acc, 0, 0, 0);
        }
        #pragma unroll
        for (int r = 0; r < 4; r++) {
            float v = acc[r] > 0.f ? acc[r] : 0.f;
            myHid[(q * 4 + r) * HSTR + col] = f2bf(v);
        }
    }
    __syncthreads();

    // ---- layer B: [16 x 128] @ wbT -> relu -> sOut (f32 LDS) ----
    bf16x8 aB[4];
    #pragma unroll
    for (int s = 0; s < 4; s++)
        aB[s] = *(const bf16x8*)&myHid[i16 * HSTR + s * 32 + q * 8];
    #pragma unroll
    for (int ct = 0; ct < 8; ct++) {
        int col = ct * 16 + i16;
        float bv = bb[col];
        f32x4 acc = (f32x4){bv, bv, bv, bv};
        #pragma unroll
        for (int s = 0; s < 4; s++) {
            bf16x8 b = *(const bf16x8*)&wbT[(size_t)col * HID + s * 32 + q * 8];
            acc = __builtin_amdgcn_mfma_f32_16x16x32_bf16(aB[s], b, acc, 0, 0, 0);
        }
        #pragma unroll
        for (int r = 0; r < 4; r++) {
            float v = acc[r] > 0.f ? acc[r] : 0.f;
            sOut[(w * 16 + q * 4 + r) * OSTR + col] = v;
        }
    }
    __syncthreads();

    // ---- epilogue (R12-proven) ----
    if (POOL) {
        if (t < HID) {
            float* psum = (float*)outv;
            float acc = 0.f;
            int curg = batch[blk0];
            for (int row = 0; row < 64; row++) {
                int node = blk0 + row;
                if (node >= N_NODES) break;
                int g = batch[node];
                if (g != curg) {
                    atomicAdd(&psum[curg * HID + t], acc);
                    acc = 0.f; curg = g;
                }
                acc += sOut[row * OSTR + t];
            }
            atomicAdd(&psum[curg * HID + t], acc);
        }
    } else {
        unsigned short* hout = (unsigned short*)outv;
        for (int idx = t; idx < 64 * 16; idx += 256) {
            int row = idx >> 4, ch = idx & 15;   // ch = 16B chunk (8 bf16)
            int node = blk0 + row;
            if (node < N_NODES) {
                float4 f0 = *(const float4*)&sOut[row * OSTR + ch * 8];
                float4 f1 = *(const float4*)&sOut[row * OSTR + ch * 8 + 4];
                uint4 u;
                u.x = (unsigned)f2bf(f0.x) | ((unsigned)f2bf(f0.y) << 16);
                u.y = (unsigned)f2bf(f0.z) | ((unsigned)f2bf(f0.w) << 16);
                u.z = (unsigned)f2bf(f1.x) | ((unsigned)f2bf(f1.y) << 16);
                u.w = (unsigned)f2bf(f1.z) | ((unsigned)f2bf(f1.w) << 16);
                *(uint4*)&hout[(size_t)node * HID + ch * 8] = u;
            }
        }
    }
}

// ---------------------------------------------------------------------------
// Pool mean: batch is SORTED -> count[g] by binary search (wave-uniform).
// ---------------------------------------------------------------------------
__global__ void pool_div_kernel(const float* __restrict__ sums,
                                const int* __restrict__ batch,
                                float* __restrict__ out) {
    int i = blockIdx.x * blockDim.x + threadIdx.x;
    if (i >= N_GRAPHS * HID) return;
    int g = i / HID;
    int lo = 0, hi = N_NODES;
    while (lo < hi) { int mid = (lo + hi) >> 1; if (batch[mid] < g) lo = mid + 1; else hi = mid; }
    int start = lo;
    lo = 0; hi = N_NODES;
    while (lo < hi) { int mid = (lo + hi) >> 1; if (batch[mid] <= g) lo = mid + 1; else hi = mid; }
    float c = (float)(lo - start);
    out[i] = sums[i] / (c > 1.0f ? c : 1.0f);
}

extern "C" void kernel_launch(void* const* d_in, const int* in_sizes, int n_in,
                              void* d_out, int out_size, void* d_ws, size_t ws_size,
                              hipStream_t stream) {
    const float* x    = (const float*)d_in[0];
    const int*   ei   = (const int*)d_in[1];
    const float* ea   = (const float*)d_in[2];
    const int*   batch= (const int*)d_in[3];
    const float* el1w = (const float*)d_in[4];
    const float* el1b = (const float*)d_in[5];
    const float* w1a  = (const float*)d_in[6];
    const float* b1a  = (const float*)d_in[7];
    const float* w1b  = (const float*)d_in[8];
    const float* b1b  = (const float*)d_in[9];
    const float* el2w = (const float*)d_in[10];
    const float* el2b = (const float*)d_in[11];
    const float* w2a  = (const float*)d_in[12];
    const float* b2a  = (const float*)d_in[13];
    const float* w2b  = (const float*)d_in[14];
    const float* b2b  = (const float*)d_in[15];
    float* out = (float*)d_out;

    // workspace layout (16B-aligned sections)
    uint2* edata    = (uint2*)d_ws;                        // [N*CAP] 8B records  25.6 MB
    float* psum     = (float*)(edata + (size_t)N_NODES * CAP);  // [G*HID] 8192 f32
    int*   deg      = (int*)(psum + N_GRAPHS * HID);       // [N]
    // ints after edata: 8192 + 50000 = 58192 (16B multiple)
    unsigned short* hbf  = (unsigned short*)((char*)psum + (size_t)58192 * 4);  // bf16 [N,HID]
    unsigned short* sgbuf= hbf + (size_t)N_NODES * HID;  // bf16 [N_PAD, 128] (layer1 uses stride 64)
    unsigned short* waT1 = sgbuf + (size_t)N_PAD * HID;  // bf16 [128, 64]
    unsigned short* wbT1 = waT1 + HID * IN_CH;           // bf16 [128, 128]
    unsigned short* waT2 = wbT1 + HID * HID;             // bf16 [128, 128]
    unsigned short* wbT2 = waT2 + HID * HID;             // bf16 [128, 128]
    unsigned short* xbf  = wbT2 + HID * HID;             // bf16 [N, 64]

    // ---- prep (1 dispatch): zero deg+psum, transpose weights, x->bf16 ----
    prep_kernel<<<(N_NODES * IN_CH) / 256, 256, 0, stream>>>(
        x, w1a, w1b, w2a, w2b, xbf, waT1, wbT1, waT2, wbT2, deg, psum);
    // ---- edge build: one dispatch, 1 edge/thread, fixed-capacity buckets ----
    build_kernel<<<(N_EDGES + 255) / 256, 256, 0, stream>>>(ei, ea, deg, edata);

    // ---- layer 1: bf16 gather -> sg ; MFMA MLP -> hbf (bf16) ----
    gather64_kernel<<<N_NODES / 4, 128, 0, stream>>>(
        xbf, edata, deg, el1w, el1b, sgbuf);
    mlp_mfma_kernel<IN_CH, false><<<N_PAD / 64, 256, 0, stream>>>(
        sgbuf, waT1, b1a, wbT1, b1b, hbf, nullptr);

    // ---- layer 2: paired-lockstep bf16 gather ; MFMA MLP + LDS pool ----
    gather128_kernel<<<N_NODES / 8, 256, 0, stream>>>(
        hbf, edata, deg, el2w, el2b, sgbuf);
    mlp_mfma_kernel<HID, true><<<N_PAD / 64, 256, 0, stream>>>(
        sgbuf, waT2, b2a, wbT2, b2b, psum, batch);

    // ---- mean (count via binary search on sorted batch) ----
    pool_div_kernel<<<(N_GRAPHS * HID + 255) / 256, 256, 0, stream>>>(psum, batch, out);
}